// Round 2
// baseline (695.883 us; speedup 1.0000x reference)
//
#include <hip/hip_runtime.h>
#include <hip/hip_bf16.h>

namespace {

constexpr int N_NODES = 100000;
constexpr int N_EDGES = 3200000;
constexpr int D = 16;
constexpr int H = 64;
constexpr int C = 10;
constexpr int L = 2;
constexpr int BLK = 256;
constexpr int NBN = (N_NODES + BLK - 1) / BLK;  // 391

__global__ void k_init(int* __restrict__ cnt, float* __restrict__ deg) {
  int i = blockIdx.x * BLK + threadIdx.x;
  if (i < N_NODES) { cnt[i] = 0; deg[i] = 1.0f; }  // deg starts at self-loop weight 1
}

__global__ void k_degcnt(const int* __restrict__ col, const float* __restrict__ ew,
                         float* __restrict__ deg, int* __restrict__ cnt) {
  int stride = gridDim.x * BLK;
  for (int i = blockIdx.x * BLK + threadIdx.x; i < N_EDGES; i += stride) {
    int c = col[i];
    atomicAdd(&deg[c], ew[i]);
    atomicAdd(&cnt[c], 1);
  }
}

__global__ void k_dinv(const float* __restrict__ deg, float* __restrict__ dinv) {
  int i = blockIdx.x * BLK + threadIdx.x;
  if (i < N_NODES) {
    float d = deg[i];
    dinv[i] = d > 0.f ? rsqrtf(fmaxf(d, 1e-30f)) : 0.f;
  }
}

// ---- 3-kernel exclusive scan of cnt -> rowptr (and cursor copy) ----
__global__ void k_scanA(const int* __restrict__ cnt, int* __restrict__ bsum) {
  __shared__ int s[BLK];
  int i = blockIdx.x * BLK + threadIdx.x;
  s[threadIdx.x] = (i < N_NODES) ? cnt[i] : 0;
  __syncthreads();
  for (int off = BLK / 2; off > 0; off >>= 1) {
    if (threadIdx.x < off) s[threadIdx.x] += s[threadIdx.x + off];
    __syncthreads();
  }
  if (threadIdx.x == 0) bsum[blockIdx.x] = s[0];
}

__global__ void k_scanB(int* __restrict__ bsum, int nb) {
  __shared__ int s[512];
  int t = threadIdx.x;
  s[t] = (t < nb) ? bsum[t] : 0;
  __syncthreads();
  for (int off = 1; off < 512; off <<= 1) {
    int v = (t >= off) ? s[t - off] : 0;
    __syncthreads();
    s[t] += v;
    __syncthreads();
  }
  if (t < nb) bsum[t] = (t > 0) ? s[t - 1] : 0;  // exclusive
}

__global__ void k_scanC(const int* __restrict__ cnt, const int* __restrict__ bsum,
                        int* __restrict__ rowptr, int* __restrict__ cursor) {
  __shared__ int s[BLK];
  int i = blockIdx.x * BLK + threadIdx.x;
  int t = threadIdx.x;
  int myv = (i < N_NODES) ? cnt[i] : 0;
  s[t] = myv;
  __syncthreads();
  for (int off = 1; off < BLK; off <<= 1) {
    int v = (t >= off) ? s[t - off] : 0;
    __syncthreads();
    s[t] += v;
    __syncthreads();
  }
  int excl = s[t] - myv + bsum[blockIdx.x];
  if (i < N_NODES) { rowptr[i] = excl; cursor[i] = excl; }
  if (i == 0) rowptr[N_NODES] = N_EDGES;
}

__global__ void k_scatter(const int* __restrict__ row, const int* __restrict__ col,
                          const float* __restrict__ ew, const float* __restrict__ dinv,
                          int* __restrict__ cursor, int* __restrict__ srow,
                          float* __restrict__ snorm) {
  int stride = gridDim.x * BLK;
  for (int e = blockIdx.x * BLK + threadIdx.x; e < N_EDGES; e += stride) {
    int r = row[e], c = col[e];
    int pos = atomicAdd(&cursor[c], 1);
    srow[pos] = r;
    snorm[pos] = dinv[r] * ew[e] * dinv[c];
  }
}

// out[v,:] = h[v,:] @ W^T
__global__ void k_lin(const float* __restrict__ hin, const float* __restrict__ W,
                      float* __restrict__ out) {
  __shared__ float sW[D * D];
  sW[threadIdx.x] = W[threadIdx.x];
  __syncthreads();
  int v = blockIdx.x * BLK + threadIdx.x;
  if (v >= N_NODES) return;
  float hv[D];
  const float4* hp = reinterpret_cast<const float4*>(hin + (size_t)v * D);
#pragma unroll
  for (int c = 0; c < 4; ++c) {
    float4 t = hp[c];
    hv[4 * c + 0] = t.x; hv[4 * c + 1] = t.y;
    hv[4 * c + 2] = t.z; hv[4 * c + 3] = t.w;
  }
  float4* op = reinterpret_cast<float4*>(out + (size_t)v * D);
#pragma unroll
  for (int jc = 0; jc < 4; ++jc) {
    float o[4];
#pragma unroll
    for (int jj = 0; jj < 4; ++jj) {
      int j = jc * 4 + jj;
      float s = 0.f;
#pragma unroll
      for (int k = 0; k < D; ++k) s += hv[k] * sW[j * D + k];
      o[jj] = s;
    }
    op[jc] = make_float4(o[0], o[1], o[2], o[3]);
  }
}

// Pull-aggregate + fused nodeNN/tanh/LeakyReLU/LayerNorm.
// block = 256 = 16 groups x 16 lanes; group g handles node v = blockIdx*16+g;
// lane l owns feature l.
__global__ void k_pull(const int* __restrict__ rowptr, const int* __restrict__ srow,
                       const float* __restrict__ snorm, const float* __restrict__ dinv,
                       const float* __restrict__ out,
                       const float* __restrict__ Wn, const float* __restrict__ nb,
                       const float* __restrict__ cb, const float* __restrict__ lg,
                       const float* __restrict__ lb, float* __restrict__ h) {
  __shared__ float sW[D * D];
  __shared__ float snb[D], scb[D], slg[D], slb[D];
  __shared__ float sagg[16][D + 1];
  sW[threadIdx.x] = Wn[threadIdx.x];
  if (threadIdx.x < D) {
    snb[threadIdx.x] = nb[threadIdx.x];
    scb[threadIdx.x] = cb[threadIdx.x];
    slg[threadIdx.x] = lg[threadIdx.x];
    slb[threadIdx.x] = lb[threadIdx.x];
  }
  __syncthreads();

  const int g = threadIdx.x >> 4;
  const int l = threadIdx.x & 15;
  const int v = blockIdx.x * 16 + g;
  const bool ok = v < N_NODES;

  float acc = 0.f;
  if (ok) {
    float dv = dinv[v];
    acc = dv * dv * out[v * D + l];  // self-loop term
    int beg = rowptr[v], end = rowptr[v + 1];
    int p = beg;
    int e4 = beg + ((end - beg) & ~3);
    for (; p < e4; p += 4) {
      int r0 = srow[p + 0], r1 = srow[p + 1], r2 = srow[p + 2], r3 = srow[p + 3];
      float n0 = snorm[p + 0], n1 = snorm[p + 1], n2 = snorm[p + 2], n3 = snorm[p + 3];
      float g0 = out[r0 * D + l], g1 = out[r1 * D + l];
      float g2 = out[r2 * D + l], g3 = out[r3 * D + l];
      acc += n0 * g0 + n1 * g1 + n2 * g2 + n3 * g3;
    }
    for (; p < end; ++p) acc += snorm[p] * out[srow[p] * D + l];
    sagg[g][l] = acc;
  }
  __syncthreads();

  if (!ok) return;
  // nodeNN: feature j = l
  float s = snb[l];
#pragma unroll
  for (int k = 0; k < D; ++k) s += sagg[g][k] * sW[l * D + k];
  float u = tanhf(s) + scb[l];
  u = u > 0.f ? u : 0.2f * u;  // LeakyReLU(0.2)

  // LayerNorm across the 16-lane group (shfl_xor stays within the group)
  float mu = u;
#pragma unroll
  for (int m = 1; m < 16; m <<= 1) mu += __shfl_xor(mu, m, 64);
  mu *= (1.0f / D);
  float d0 = u - mu;
  float var = d0 * d0;
#pragma unroll
  for (int m = 1; m < 16; m <<= 1) var += __shfl_xor(var, m, 64);
  var *= (1.0f / D);
  float inv = rsqrtf(var + 1e-5f);
  h[v * D + l] = d0 * inv * slg[l] + slb[l];
}

// out[v,:] = relu(h @ w1^T + b1) @ w2^T + b2
__global__ void k_cls(const float* __restrict__ h, const float* __restrict__ w1,
                      const float* __restrict__ b1, const float* __restrict__ w2,
                      const float* __restrict__ b2, float* __restrict__ out) {
  __shared__ float sw1[H * D];
  __shared__ float sb1[H];
  __shared__ float sw2[C * H];
  __shared__ float sb2[C];
  for (int i = threadIdx.x; i < H * D; i += BLK) sw1[i] = w1[i];
  for (int i = threadIdx.x; i < H; i += BLK) sb1[i] = b1[i];
  for (int i = threadIdx.x; i < C * H; i += BLK) sw2[i] = w2[i];
  for (int i = threadIdx.x; i < C; i += BLK) sb2[i] = b2[i];
  __syncthreads();
  int v = blockIdx.x * BLK + threadIdx.x;
  if (v >= N_NODES) return;
  float hv[D];
  const float4* hp = reinterpret_cast<const float4*>(h + (size_t)v * D);
#pragma unroll
  for (int c = 0; c < 4; ++c) {
    float4 t = hp[c];
    hv[4 * c + 0] = t.x; hv[4 * c + 1] = t.y;
    hv[4 * c + 2] = t.z; hv[4 * c + 3] = t.w;
  }
  float oc[C];
#pragma unroll
  for (int c = 0; c < C; ++c) oc[c] = sb2[c];
#pragma unroll
  for (int j = 0; j < H; ++j) {
    float s = sb1[j];
#pragma unroll
    for (int k = 0; k < D; ++k) s += hv[k] * sw1[j * D + k];
    s = fmaxf(s, 0.f);
#pragma unroll
    for (int c = 0; c < C; ++c) oc[c] += s * sw2[c * H + j];
  }
#pragma unroll
  for (int c = 0; c < C; ++c) out[(size_t)v * C + c] = oc[c];
}

inline char* align_up(char* p, size_t a) {
  return (char*)(((uintptr_t)p + a - 1) & ~(uintptr_t)(a - 1));
}

}  // namespace

extern "C" void kernel_launch(void* const* d_in, const int* in_sizes, int n_in,
                              void* d_out, int out_size, void* d_ws, size_t ws_size,
                              hipStream_t stream) {
  const float* x         = (const float*)d_in[0];
  const int*   edge_idx  = (const int*)d_in[1];   // [2, E]
  const float* edge_attr = (const float*)d_in[2];
  const float* lin_w  = (const float*)d_in[4];
  const float* conv_b = (const float*)d_in[5];
  const float* node_w = (const float*)d_in[6];
  const float* node_b = (const float*)d_in[7];
  const float* ln_g   = (const float*)d_in[8];
  const float* ln_b   = (const float*)d_in[9];
  const float* w1     = (const float*)d_in[10];
  const float* b1     = (const float*)d_in[11];
  const float* w2     = (const float*)d_in[12];
  const float* b2     = (const float*)d_in[13];
  float* out = (float*)d_out;

  const int* row = edge_idx;            // source
  const int* col = edge_idx + N_EDGES;  // target

  // workspace layout (256B-aligned regions)
  char* p = (char*)d_ws;
  int*   cnt    = (int*)p;    p = align_up(p + sizeof(int) * N_NODES, 256);
  float* deg    = (float*)p;  p = align_up(p + sizeof(float) * N_NODES, 256);
  float* dinv   = (float*)p;  p = align_up(p + sizeof(float) * N_NODES, 256);
  int*   rowptr = (int*)p;    p = align_up(p + sizeof(int) * (N_NODES + 1), 256);
  int*   cursor = (int*)p;    p = align_up(p + sizeof(int) * N_NODES, 256);
  int*   bsum   = (int*)p;    p = align_up(p + sizeof(int) * 512, 256);
  int*   srow   = (int*)p;    p = align_up(p + sizeof(int) * N_EDGES, 256);
  float* snorm  = (float*)p;  p = align_up(p + sizeof(float) * N_EDGES, 256);
  float* outb   = (float*)p;  p = align_up(p + sizeof(float) * (size_t)N_NODES * D, 256);
  float* hbuf   = (float*)p;  p = align_up(p + sizeof(float) * (size_t)N_NODES * D, 256);

  const int nbE = 4096;

  // ---- one-time CSR build (graph structure is layer-independent) ----
  k_init<<<NBN, BLK, 0, stream>>>(cnt, deg);
  k_degcnt<<<nbE, BLK, 0, stream>>>(col, edge_attr, deg, cnt);
  k_dinv<<<NBN, BLK, 0, stream>>>(deg, dinv);
  k_scanA<<<NBN, BLK, 0, stream>>>(cnt, bsum);
  k_scanB<<<1, 512, 0, stream>>>(bsum, NBN);
  k_scanC<<<NBN, BLK, 0, stream>>>(cnt, bsum, rowptr, cursor);
  k_scatter<<<nbE, BLK, 0, stream>>>(row, col, edge_attr, dinv, cursor, srow, snorm);

  // ---- layers ----
  for (int i = 0; i < L; ++i) {
    const float* hin = (i == 0) ? x : hbuf;
    k_lin<<<NBN, BLK, 0, stream>>>(hin, lin_w + i * D * D, outb);
    k_pull<<<(N_NODES + 15) / 16, BLK, 0, stream>>>(
        rowptr, srow, snorm, dinv, outb,
        node_w + i * D * D, node_b + i * D, conv_b + i * D,
        ln_g + i * D, ln_b + i * D, hbuf);
  }
  k_cls<<<NBN, BLK, 0, stream>>>(hbuf, w1, b1, w2, b2, out);
}